// Round 3
// baseline (2279.238 us; speedup 1.0000x reference)
//
#include <hip/hip_runtime.h>
#include <hip/hip_bf16.h>

#define SEQ  2048
#define BAT  64
#define HID  128
#define LDSP 136   // padded LDS row: 272 B

// workspace layout (needs ~36 MiB, proven available earlier)
#define XB_OFF  (1u << 20)            // bf16 x, 32 MiB
#define IL_OFF  (35u << 20)           // f32 ilogm1[t][b], 512 KiB

typedef __bf16 bf16x8 __attribute__((ext_vector_type(8)));
typedef float  f32x4  __attribute__((ext_vector_type(4)));

#define MFMA(a,b,c) __builtin_amdgcn_mfma_f32_16x16x32_bf16((a),(b),(c),0,0,0)

__device__ __forceinline__ float sig_f(float x) {
    return __fdividef(1.0f, 1.0f + __expf(-x));
}
__device__ __forceinline__ float tanh_f(float x) {
    return 1.0f - __fdividef(2.0f, 1.0f + __expf(2.0f * x));
}
__device__ __forceinline__ bf16x8 cvt8(const float* p) {
    bf16x8 r;
    #pragma unroll
    for (int i = 0; i < 8; ++i) r[i] = (__bf16)p[i];
    return r;
}

// ---- pre-kernel 1: x f32 -> bf16, same [S][B][I] layout ----
__global__ void cvt_x_kernel(const float* __restrict__ x, __bf16* __restrict__ xb) {
    const int i = (blockIdx.x * 256 + threadIdx.x) * 4;
    const float4 v = *reinterpret_cast<const float4*>(x + i);
    __bf16 o[4];
    o[0] = (__bf16)v.x; o[1] = (__bf16)v.y; o[2] = (__bf16)v.z; o[3] = (__bf16)v.w;
    *reinterpret_cast<uint2*>(xb + i) = *reinterpret_cast<const uint2*>(o);
}

// ---- pre-kernel 2: ilogm1[t][b] = 1/ln(e + dts[b][t]) - 1 ----
__global__ void prep_ilog_kernel(const float* __restrict__ dts, float* __restrict__ il) {
    const int idx = blockIdx.x * 256 + threadIdx.x;
    const int b = idx >> 11, t = idx & 2047;
    const float l = __logf(2.718281828459045f + dts[idx]);
    il[t * BAT + b] = __fdividef(1.0f, l) - 1.0f;
}

// 32 WGs: blockIdx = dir*16 + batch_tile; each WG owns 4 chains.
// MERGED hc A-tile: h chains at rows {0,4,8,12}, c chains at rows {1,5,9,13}; one
// ds_read_b128 per kt feeds all 5 recurrent MFMAs (gates read h-rows -> C reg 0;
// W_d reads c-rows -> C reg 1). Pad rows never contaminate valid rows (D row m
// sums only A row m).
// TIME-BATCHED x: x A-tile packs 4 timesteps x 4 chains (row = 4*chain + dt), so
// ONE 16-MFMA block yields x-gate pre-acts for 4 steps; C reg r of lane q =
// (chain q, step dt=r). Spread 4 x-MFMAs per step (kt=dt), consumed next window.
// Per-wave MFMA/step: 20 (h/c) + 4 (x) = 24, down from 36.
__global__ __launch_bounds__(512, 2) void tlstm_main(
    const __bf16* __restrict__ xb,   const float* __restrict__ ilg,
    const float* __restrict__ h0,    const float* __restrict__ c0,
    const float* __restrict__ Wih_f, const float* __restrict__ Whh_f,
    const float* __restrict__ bih_f, const float* __restrict__ bhh_f,
    const float* __restrict__ Wd_f,  const float* __restrict__ bd_f,
    const float* __restrict__ Wih_r, const float* __restrict__ Whh_r,
    const float* __restrict__ bih_r, const float* __restrict__ bhh_r,
    const float* __restrict__ Wd_r,  const float* __restrict__ bd_r,
    float* __restrict__ out)
{
    const int d    = blockIdx.x >> 4;
    const int b0   = (blockIdx.x & 15) * 4;
    const int tid  = threadIdx.x;
    const int w    = tid >> 6;
    const int lane = tid & 63;
    const int nl   = lane & 15;
    const int q    = lane >> 4;
    const int j    = w * 16 + nl;

    const float* Wih = d ? Wih_r : Wih_f;
    const float* Whh = d ? Whh_r : Whh_f;
    const float* bih = d ? bih_r : bih_f;
    const float* bhh = d ? bhh_r : bhh_f;
    const float* Wd  = d ? Wd_r  : Wd_f;
    const float* bd  = d ? bd_r  : bd_f;

    __shared__ __align__(16) __bf16 hc_a[2][16][LDSP];

    // resident weight B-frags: B[k][n] = W[n][k]; lane: n=nl(->j), k = kt*32 + q*8 ..+8
    bf16x8 whh_fr[4][4], wih_fr[4][4], wd_fr[4];
    #pragma unroll
    for (int g = 0; g < 4; ++g) {
        const int row = g * 128 + j;
        #pragma unroll
        for (int kt = 0; kt < 4; ++kt) {
            const int off = row * HID + kt * 32 + q * 8;
            wih_fr[g][kt] = cvt8(Wih + off);
            whh_fr[g][kt] = cvt8(Whh + off);
        }
    }
    #pragma unroll
    for (int kt = 0; kt < 4; ++kt)
        wd_fr[kt] = cvt8(Wd + j * HID + kt * 32 + q * 8);

    float bias_g[4];
    #pragma unroll
    for (int g = 0; g < 4; ++g)
        bias_g[g] = bih[g * 128 + j] + bhh[g * 128 + j];
    const float bias_d = bd[j];

    // initial state: h rows {0,4,8,12}, c rows {1,5,9,13}
    for (int e = tid; e < 4 * HID; e += 512) {
        const int ci = e >> 7, k = e & 127;
        hc_a[0][ci * 4][k]     = (__bf16)h0[(d * BAT + b0 + ci) * HID + k];
        hc_a[0][ci * 4 + 1][k] = (__bf16)c0[(d * BAT + b0 + ci) * HID + k];
    }
    float c_st = c0[(d * BAT + b0 + q) * HID + j];
    __syncthreads();

    // running pointers
    const int t0      = d ? (SEQ - 1) : 0;
    const int tstep   = d ? -1 : 1;
    const int xstride = tstep * BAT * HID;
    const int istride = tstep * BAT;
    const int ostride = tstep * BAT * 256;

    // x A-row = 4*chain + dt: chain = nl>>2, dt = nl&3 (window-local timestep)
    const __bf16* xp0 = xb + (size_t)((t0 + tstep * (nl & 3)) * BAT + b0 + (nl >> 2)) * HID + q * 8;
    const float*  ip0 = ilg + (size_t)t0 * BAT + b0 + q;
    float*        op  = out + (size_t)(t0 * BAT + b0 + q) * 256 + d * 128 + j;

    // ---- pipeline state ----
    bf16x8 xfrA[4], xfrB[4];      // x frags: one set = one 4-step window
    f32x4  xaccA[4], xaccB[4];    // x-gate pre-acts: reg r = step dt=r of the window
    float  ilA[4], ilB[4];

    // prologue: window-0 gates directly
    {
        bf16x8 x0[4];
        #pragma unroll
        for (int kt = 0; kt < 4; ++kt)
            x0[kt] = *reinterpret_cast<const bf16x8*>(xp0 + kt * 32);
        #pragma unroll
        for (int g = 0; g < 4; ++g)
            xaccA[g] = f32x4{bias_g[g], bias_g[g], bias_g[g], bias_g[g]};
        #pragma unroll
        for (int kt = 0; kt < 4; ++kt) {
            xaccA[0] = MFMA(x0[kt], wih_fr[0][kt], xaccA[0]);
            xaccA[1] = MFMA(x0[kt], wih_fr[1][kt], xaccA[1]);
            xaccA[2] = MFMA(x0[kt], wih_fr[2][kt], xaccA[2]);
            xaccA[3] = MFMA(x0[kt], wih_fr[3][kt], xaccA[3]);
        }
    }
    // window-1 frags
    #pragma unroll
    for (int kt = 0; kt < 4; ++kt)
        xfrA[kt] = *reinterpret_cast<const bf16x8*>(xp0 + 4 * xstride + kt * 32);
    // window-0 il
    #pragma unroll
    for (int dt = 0; dt < 4; ++dt)
        ilA[dt] = ip0[dt * istride];

    const __bf16* xpl = xp0 + 8 * xstride;   // frag loads target window w+2
    const float*  ipl = ip0 + 4 * istride;   // il loads target window w+1

    // one 4-step window; xaccCur/xfrUse consumed, xaccNext built, xfrLd/ilNext loaded
    auto window = [&](f32x4 (&xaccCur)[4], f32x4 (&xaccNext)[4],
                      bf16x8 (&xfrUse)[4], bf16x8 (&xfrLd)[4],
                      float (&ilCur)[4], float (&ilNext)[4]) __attribute__((always_inline)) {
        #pragma unroll
        for (int dt = 0; dt < 4; ++dt) {
            const int p = dt & 1;

            // issue recurrent-tile reads first
            bf16x8 hcfr[4];
            #pragma unroll
            for (int kt = 0; kt < 4; ++kt)
                hcfr[kt] = *reinterpret_cast<const bf16x8*>(&hc_a[p][nl][kt * 32 + q * 8]);

            // next-window x contribution (independent of LDS): kt = dt
            {
                const bf16x8 xf = xfrUse[dt];
                if (dt == 0) {
                    #pragma unroll
                    for (int g = 0; g < 4; ++g) {
                        const f32x4 binit = f32x4{bias_g[g], bias_g[g], bias_g[g], bias_g[g]};
                        xaccNext[g] = MFMA(xf, wih_fr[g][0], binit);
                    }
                } else {
                    #pragma unroll
                    for (int g = 0; g < 4; ++g)
                        xaccNext[g] = MFMA(xf, wih_fr[g][dt], xaccNext[g]);
                }
            }

            // C-in: reg 0 must carry this step's x-pre (lane's own xaccCur[g][dt])
            f32x4 ai, af, ag, ao;
            {
                const float s0 = xaccCur[0][dt], s1 = xaccCur[1][dt];
                const float s2 = xaccCur[2][dt], s3 = xaccCur[3][dt];
                ai = f32x4{s0, s0, s0, s0};
                af = f32x4{s1, s1, s1, s1};
                ag = f32x4{s2, s2, s2, s2};
                ao = f32x4{s3, s3, s3, s3};
            }
            f32x4 acs = f32x4{bias_d, bias_d, bias_d, bias_d};
            #pragma unroll
            for (int kt = 0; kt < 4; ++kt) {
                ai  = MFMA(hcfr[kt], whh_fr[0][kt], ai);
                af  = MFMA(hcfr[kt], whh_fr[1][kt], af);
                ag  = MFMA(hcfr[kt], whh_fr[2][kt], ag);
                ao  = MFMA(hcfr[kt], whh_fr[3][kt], ao);
                acs = MFMA(hcfr[kt], wd_fr[kt], acs);
            }

            // prefetch: window+2 frag slice, window+1 il
            xfrLd[dt]  = *reinterpret_cast<const bf16x8*>(xpl + dt * 32);
            ilNext[dt] = ipl[dt * istride];

            // epilogue: gates at C reg 0 (h-row 4q); c_s at C reg 1 (c-row 4q+1)
            const int pn = p ^ 1;
            {
                const float cs   = tanh_f(acs[1]);
                const float cadj = fmaf(cs, ilCur[dt], c_st);
                const float gi   = sig_f(ai[0]);
                const float gf   = sig_f(af[0]);
                const float gg   = tanh_f(ag[0]);
                const float go   = sig_f(ao[0]);
                const float cn   = gf * cadj + gi * gg;
                const float hn   = go * tanh_f(cn);
                c_st = cn;
                hc_a[pn][q * 4][j]     = (__bf16)hn;
                hc_a[pn][q * 4 + 1][j] = (__bf16)cn;
                *op = hn;
            }
            op += ostride;

            // order LDS ops only; keep global loads/stores in flight across the barrier
            asm volatile("s_waitcnt lgkmcnt(0)\n\ts_barrier" ::: "memory");
        }
        xpl += 4 * xstride;
        ipl += 4 * istride;
    };

    for (int wn = 0; wn < SEQ / 4; wn += 2) {
        window(xaccA, xaccB, xfrA, xfrB, ilA, ilB);
        window(xaccB, xaccA, xfrB, xfrA, ilB, ilA);
    }
}

extern "C" void kernel_launch(void* const* d_in, const int* in_sizes, int n_in,
                              void* d_out, int out_size, void* d_ws, size_t ws_size,
                              hipStream_t stream) {
    const float* x     = (const float*)d_in[0];
    const float* h0    = (const float*)d_in[1];
    const float* c0    = (const float*)d_in[2];
    const float* dts   = (const float*)d_in[3];
    const float* Wih_f = (const float*)d_in[4];
    const float* Whh_f = (const float*)d_in[5];
    const float* bih_f = (const float*)d_in[6];
    const float* bhh_f = (const float*)d_in[7];
    const float* Wd_f  = (const float*)d_in[8];
    const float* bd_f  = (const float*)d_in[9];
    const float* Wih_r = (const float*)d_in[10];
    const float* Whh_r = (const float*)d_in[11];
    const float* bih_r = (const float*)d_in[12];
    const float* bhh_r = (const float*)d_in[13];
    const float* Wd_r  = (const float*)d_in[14];
    const float* bd_r  = (const float*)d_in[15];
    float* out = (float*)d_out;

    __bf16* xbuf = (__bf16*)((char*)d_ws + XB_OFF);
    float*  il   = (float*)((char*)d_ws + IL_OFF);

    cvt_x_kernel<<<16384, 256, 0, stream>>>(x, xbuf);
    prep_ilog_kernel<<<512, 256, 0, stream>>>(dts, il);

    tlstm_main<<<32, 512, 0, stream>>>(xbuf, il, h0, c0,
                                       Wih_f, Whh_f, bih_f, bhh_f, Wd_f, bd_f,
                                       Wih_r, Whh_r, bih_r, bhh_r, Wd_r, bd_r,
                                       out);
}

// Round 4
// 1829.449 us; speedup vs baseline: 1.2459x; 1.2459x over previous
//
#include <hip/hip_runtime.h>
#include <hip/hip_bf16.h>

#define SEQ  2048
#define BAT  64
#define HID  128
#define LDSP 136   // padded LDS row: 272 B

// workspace layout (needs ~36 MiB, proven available earlier; 1 MiB guard before XB)
#define XB_OFF  (1u << 20)            // bf16 x, 32 MiB
#define IL_OFF  (35u << 20)           // f32 ilogm1[t][b], 512 KiB

typedef __bf16 bf16x8 __attribute__((ext_vector_type(8)));
typedef float  f32x4  __attribute__((ext_vector_type(4)));

#define MFMA(a,b,c) __builtin_amdgcn_mfma_f32_16x16x32_bf16((a),(b),(c),0,0,0)

__device__ __forceinline__ float sig_f(float x) {
    return __fdividef(1.0f, 1.0f + __expf(-x));
}
__device__ __forceinline__ float tanh_f(float x) {
    return 1.0f - __fdividef(2.0f, 1.0f + __expf(2.0f * x));
}
__device__ __forceinline__ bf16x8 cvt8(const float* p) {
    bf16x8 r;
    #pragma unroll
    for (int i = 0; i < 8; ++i) r[i] = (__bf16)p[i];
    return r;
}

// ---- pre-kernel 1: x f32 -> bf16, same [S][B][I] layout ----
__global__ void cvt_x_kernel(const float* __restrict__ x, __bf16* __restrict__ xb) {
    const int i = (blockIdx.x * 256 + threadIdx.x) * 4;
    const float4 v = *reinterpret_cast<const float4*>(x + i);
    __bf16 o[4];
    o[0] = (__bf16)v.x; o[1] = (__bf16)v.y; o[2] = (__bf16)v.z; o[3] = (__bf16)v.w;
    *reinterpret_cast<uint2*>(xb + i) = *reinterpret_cast<const uint2*>(o);
}

// ---- pre-kernel 2: ilogm1[t][b] = 1/ln(e + dts[b][t]) - 1 ----
__global__ void prep_ilog_kernel(const float* __restrict__ dts, float* __restrict__ il) {
    const int idx = blockIdx.x * 256 + threadIdx.x;
    const int b = idx >> 11, t = idx & 2047;
    const float l = __logf(2.718281828459045f + dts[idx]);
    il[t * BAT + b] = __fdividef(1.0f, l) - 1.0f;
}

// 32 WGs: blockIdx = dir*16 + batch_tile; each WG owns 4 chains; 8 waves, wave w
// owns gate dims j in [16w, 16w+16).
//
// x-BURST: per 4-step chunk, one dense 16-MFMA block computes x@Wih + bias for all
// 4 steps. A-rows = 4*chain + dt (lane's global x row offset by nl&3), so C reg r
// of lane q = (chain q, step dt=r). 4 independent chains of 4 MFMAs; also covers
// the post-barrier ds_read latency of step 0.
//
// ROW-ROTATED hc tile: at step dt, h(chain c) lives at row 4c+dt and c(chain c)
// at row 4c+((dt+2)&3); each step writes the NEXT step's rows (4c+((dt+1)&3),
// 4c+((dt+3)&3)). Hence the gate MFMA's real output is at reg dt, so C-in is the
// burst accumulator xacc[g] VERBATIM (reg dt = this step's x-pre; other regs feed
// pad rows that are never read). Zero per-step C-init VALU. cs read at reg
// (dt+2)&3. All offsets compile-time (dt-unrolled). D row m sums only A row m,
// so stale/pad rows never contaminate valid rows.
//
// Per-wave MFMA/step: 20 recurrent + 4 amortized burst = 24 (R1 had 36).
__global__ __launch_bounds__(512, 2) void tlstm_main(
    const __bf16* __restrict__ xb,   const float* __restrict__ ilg,
    const float* __restrict__ h0,    const float* __restrict__ c0,
    const float* __restrict__ Wih_f, const float* __restrict__ Whh_f,
    const float* __restrict__ bih_f, const float* __restrict__ bhh_f,
    const float* __restrict__ Wd_f,  const float* __restrict__ bd_f,
    const float* __restrict__ Wih_r, const float* __restrict__ Whh_r,
    const float* __restrict__ bih_r, const float* __restrict__ bhh_r,
    const float* __restrict__ Wd_r,  const float* __restrict__ bd_r,
    float* __restrict__ out)
{
    const int d    = blockIdx.x >> 4;
    const int b0   = (blockIdx.x & 15) * 4;
    const int tid  = threadIdx.x;
    const int w    = tid >> 6;
    const int lane = tid & 63;
    const int nl   = lane & 15;
    const int q    = lane >> 4;
    const int j    = w * 16 + nl;

    const float* Wih = d ? Wih_r : Wih_f;
    const float* Whh = d ? Whh_r : Whh_f;
    const float* bih = d ? bih_r : bih_f;
    const float* bhh = d ? bhh_r : bhh_f;
    const float* Wd  = d ? Wd_r  : Wd_f;
    const float* bd  = d ? bd_r  : bd_f;

    __shared__ __align__(16) __bf16 hc_a[2][16][LDSP];

    // resident weight B-frags: B[k][n] = W[n][k]; lane: n=nl(->j), k = kt*32 + q*8 ..+8
    bf16x8 whh_fr[4][4], wih_fr[4][4], wd_fr[4];
    #pragma unroll
    for (int g = 0; g < 4; ++g) {
        const int row = g * 128 + j;
        #pragma unroll
        for (int kt = 0; kt < 4; ++kt) {
            const int off = row * HID + kt * 32 + q * 8;
            wih_fr[g][kt] = cvt8(Wih + off);
            whh_fr[g][kt] = cvt8(Whh + off);
        }
    }
    #pragma unroll
    for (int kt = 0; kt < 4; ++kt)
        wd_fr[kt] = cvt8(Wd + j * HID + kt * 32 + q * 8);

    float bias_g[4];
    #pragma unroll
    for (int g = 0; g < 4; ++g)
        bias_g[g] = bih[g * 128 + j] + bhh[g * 128 + j];
    const float bias_d = bd[j];
    const f32x4 bdv = f32x4{bias_d, bias_d, bias_d, bias_d};   // loop-invariant

    // initial state for step 0 (dt=0): h at rows 4c+0, c at rows 4c+2
    for (int e = tid; e < 4 * HID; e += 512) {
        const int ci = e >> 7, k = e & 127;
        hc_a[0][ci * 4][k]     = (__bf16)h0[(d * BAT + b0 + ci) * HID + k];
        hc_a[0][ci * 4 + 2][k] = (__bf16)c0[(d * BAT + b0 + ci) * HID + k];
    }
    float c_st = c0[(d * BAT + b0 + q) * HID + j];
    __syncthreads();

    // running pointers
    const int t0      = d ? (SEQ - 1) : 0;
    const int tstep   = d ? -1 : 1;
    const int xstride = tstep * BAT * HID;
    const int istride = tstep * BAT;
    const int ostride = tstep * BAT * 256;

    // burst A-row = 4*chain + dt: chain = nl>>2, dt = nl&3
    const __bf16* xp0 = xb + (size_t)((t0 + tstep * (nl & 3)) * BAT + b0 + (nl >> 2)) * HID + q * 8;
    const float*  ip0 = ilg + (size_t)t0 * BAT + b0 + q;
    float*        op  = out + (size_t)(t0 * BAT + b0 + q) * 256 + d * 128 + j;

    // ---- pipeline state: chunk double-buffer, reload-own-buffer (distance 2 chunks)
    bf16x8 xfrA[4], xfrB[4];
    float  ilA[4], ilB[4];

    #pragma unroll
    for (int kt = 0; kt < 4; ++kt) {
        xfrA[kt] = *reinterpret_cast<const bf16x8*>(xp0 + kt * 32);                // chunk 0
        xfrB[kt] = *reinterpret_cast<const bf16x8*>(xp0 + 4 * xstride + kt * 32);  // chunk 1
    }
    #pragma unroll
    for (int dtv = 0; dtv < 4; ++dtv) {
        ilA[dtv] = ip0[dtv * istride];
        ilB[dtv] = ip0[(4 + dtv) * istride];
    }
    const __bf16* xpl = xp0 + 8 * xstride;   // loads target chunk n+2
    const float*  ipl = ip0 + 8 * istride;

    auto chunk = [&](bf16x8 (&xfrCur)[4], float (&ilCur)[4]) __attribute__((always_inline)) {
        // ---- burst: x-gate pre-acts for this chunk's 4 steps (reg r = step r) ----
        f32x4 xacc[4];
        #pragma unroll
        for (int g = 0; g < 4; ++g) {
            const f32x4 bg = f32x4{bias_g[g], bias_g[g], bias_g[g], bias_g[g]};
            xacc[g] = MFMA(xfrCur[0], wih_fr[g][0], bg);
        }
        #pragma unroll
        for (int kt = 1; kt < 4; ++kt) {
            xacc[0] = MFMA(xfrCur[kt], wih_fr[0][kt], xacc[0]);
            xacc[1] = MFMA(xfrCur[kt], wih_fr[1][kt], xacc[1]);
            xacc[2] = MFMA(xfrCur[kt], wih_fr[2][kt], xacc[2]);
            xacc[3] = MFMA(xfrCur[kt], wih_fr[3][kt], xacc[3]);
        }

        #pragma unroll
        for (int dt = 0; dt < 4; ++dt) {
            const int p  = dt & 1;
            const int pn = p ^ 1;
            const int hr = dt;              // gates' real C/D reg
            const int cr = (dt + 2) & 3;    // cs real C/D reg

            const float il_use = ilCur[dt];   // read before reload overwrites

            bf16x8 hcfr[4];
            #pragma unroll
            for (int kt = 0; kt < 4; ++kt)
                hcfr[kt] = *reinterpret_cast<const bf16x8*>(&hc_a[p][nl][kt * 32 + q * 8]);

            // C-in = burst accumulators VERBATIM (reg dt carries this step's x-pre)
            f32x4 ai = xacc[0], af = xacc[1], ag = xacc[2], ao = xacc[3];
            f32x4 acs = bdv;
            #pragma unroll
            for (int kt = 0; kt < 4; ++kt) {
                ai  = MFMA(hcfr[kt], whh_fr[0][kt], ai);
                af  = MFMA(hcfr[kt], whh_fr[1][kt], af);
                ag  = MFMA(hcfr[kt], whh_fr[2][kt], ag);
                ao  = MFMA(hcfr[kt], whh_fr[3][kt], ao);
                acs = MFMA(hcfr[kt], wd_fr[kt], acs);
            }

            // prefetch chunk n+2: one x slice + one il per step into OWN buffers
            xfrCur[dt] = *reinterpret_cast<const bf16x8*>(xpl + dt * 32);
            ilCur[dt]  = ipl[dt * istride];

            // epilogue: gates at reg hr (row 4q+dt); cs at reg cr (row 4q+(dt+2)&3)
            {
                const float cs   = tanh_f(acs[cr]);
                const float cadj = fmaf(cs, il_use, c_st);
                const float gi   = sig_f(ai[hr]);
                const float gf   = sig_f(af[hr]);
                const float gg   = tanh_f(ag[hr]);
                const float go   = sig_f(ao[hr]);
                const float cn   = gf * cadj + gi * gg;
                const float hn   = go * tanh_f(cn);
                c_st = cn;
                hc_a[pn][q * 4 + ((dt + 1) & 3)][j] = (__bf16)hn;
                hc_a[pn][q * 4 + ((dt + 3) & 3)][j] = (__bf16)cn;
                *op = hn;
            }
            op += ostride;

            // order LDS ops only; keep global loads/stores in flight across the barrier
            asm volatile("s_waitcnt lgkmcnt(0)\n\ts_barrier" ::: "memory");
        }
        xpl += 4 * xstride;
        ipl += 4 * istride;
    };

    for (int tc = 0; tc < SEQ / 4; tc += 2) {
        chunk(xfrA, ilA);
        chunk(xfrB, ilB);
    }
}

extern "C" void kernel_launch(void* const* d_in, const int* in_sizes, int n_in,
                              void* d_out, int out_size, void* d_ws, size_t ws_size,
                              hipStream_t stream) {
    const float* x     = (const float*)d_in[0];
    const float* h0    = (const float*)d_in[1];
    const float* c0    = (const float*)d_in[2];
    const float* dts   = (const float*)d_in[3];
    const float* Wih_f = (const float*)d_in[4];
    const float* Whh_f = (const float*)d_in[5];
    const float* bih_f = (const float*)d_in[6];
    const float* bhh_f = (const float*)d_in[7];
    const float* Wd_f  = (const float*)d_in[8];
    const float* bd_f  = (const float*)d_in[9];
    const float* Wih_r = (const float*)d_in[10];
    const float* Whh_r = (const float*)d_in[11];
    const float* bih_r = (const float*)d_in[12];
    const float* bhh_r = (const float*)d_in[13];
    const float* Wd_r  = (const float*)d_in[14];
    const float* bd_r  = (const float*)d_in[15];
    float* out = (float*)d_out;

    __bf16* xbuf = (__bf16*)((char*)d_ws + XB_OFF);
    float*  il   = (float*)((char*)d_ws + IL_OFF);

    cvt_x_kernel<<<16384, 256, 0, stream>>>(x, xbuf);
    prep_ilog_kernel<<<512, 256, 0, stream>>>(dts, il);

    tlstm_main<<<32, 512, 0, stream>>>(xbuf, il, h0, c0,
                                       Wih_f, Whh_f, bih_f, bhh_f, Wd_f, bd_f,
                                       Wih_r, Whh_r, bih_r, bhh_r, Wd_r, bd_r,
                                       out);
}